// Round 2
// baseline (17424.651 us; speedup 1.0000x reference)
//
#include <hip/hip_runtime.h>

// GMAN-ish pipeline, fully fused. support = I so every (b,n) token is independent.
// B=64, P=Q=12, N=1024, D=64. Output [B,Q,N] fp32.
//
// R2: kill register spills (R1: 2.33 GB scratch traffic, VALU 22%).
//  - s1/s2 states live in LDS, k-major [64][256]: lane owns its column, no barriers,
//    conflict-free (2 lanes/bank), streamed 1 float per k-iteration.
//  - gates computed in two passes (r then u) so peak live regs = xe64+ga64+c64 ~ 192.

#define NB 1024

__device__ __forceinline__ float fexp(float x) {
    return __builtin_amdgcn_exp2f(x * 1.44269504088896341f);
}
__device__ __forceinline__ float fsigmoid(float x) {
    return __builtin_amdgcn_rcpf(1.0f + fexp(-x));   // exp overflow -> inf -> rcp -> 0 : OK
}
__device__ __forceinline__ float ftanh(float x) {
    return 1.0f - 2.0f * __builtin_amdgcn_rcpf(1.0f + fexp(2.0f * x));  // saturates to +-1 : OK
}

// ---- collapse one DCGRU layer's weights: Wx = W[0:64]+W[128:192], Ws = W[64:128]+W[192:256]
// out layout (floats): Wgx [0,8192) Wgs [8192,16384) Wcx [16384,20480) Wcs [20480,24576)
__global__ void prep_weights(const float* __restrict__ Wg, const float* __restrict__ Wc,
                             float* __restrict__ o) {
    int i = blockIdx.x * 256 + threadIdx.x;
    if (i >= 24576) return;
    if (i < 8192) {
        int k = i >> 7, j = i & 127;
        o[i] = Wg[k * 128 + j] + Wg[(128 + k) * 128 + j];
    } else if (i < 16384) {
        int ii = i - 8192; int k = ii >> 7, j = ii & 127;
        o[i] = Wg[(64 + k) * 128 + j] + Wg[(192 + k) * 128 + j];
    } else if (i < 20480) {
        int ii = i - 16384; int k = ii >> 6, j = ii & 63;
        o[i] = Wc[k * 64 + j] + Wc[(128 + k) * 64 + j];
    } else {
        int ii = i - 20480; int k = ii >> 6, j = ii & 63;
        o[i] = Wc[(64 + k) * 64 + j] + Wc[(192 + k) * 64 + j];
    }
}

// ---- se = relu(SE@W1+b1)@W2+b2, stored TRANSPOSED [d][n] with b_in2 folded in.
__global__ void prep_se(const float* __restrict__ SE, const float* __restrict__ W1,
                        const float* __restrict__ b1, const float* __restrict__ W2,
                        const float* __restrict__ b2, const float* __restrict__ bin2,
                        float* __restrict__ seT) {
    __shared__ float h[64];
    int n = blockIdx.x, d = threadIdx.x;
    float acc = b1[d];
    for (int k = 0; k < 64; k++) acc = fmaf(SE[n * 64 + k], W1[k * 64 + d], acc);
    h[d] = fmaxf(acc, 0.0f);
    __syncthreads();
    float acc2 = b2[d];
    for (int k = 0; k < 64; k++) acc2 = fmaf(h[k], W2[k * 64 + d], acc2);
    seT[d * NB + n] = acc2 + bin2[d];
}

// ---- te[b,p,:] = relu(Wte1[dow]+Wte1[7+tod]+b1)@W2+b2   (one-hot matmul == row gather)
__global__ void prep_te(const int* __restrict__ TE, const float* __restrict__ W1,
                        const float* __restrict__ b1, const float* __restrict__ W2,
                        const float* __restrict__ b2, float* __restrict__ teo) {
    __shared__ float h[64];
    int bp = blockIdx.x;            // b*12 + p
    int b = bp / 12, p = bp - b * 12;
    int d = threadIdx.x;
    int dow = TE[(b * 24 + p) * 2 + 0];
    int tod = TE[(b * 24 + p) * 2 + 1];
    float v = W1[dow * 64 + d] + W1[(7 + tod) * 64 + d] + b1[d];
    h[d] = fmaxf(v, 0.0f);
    __syncthreads();
    float acc = b2[d];
    for (int k = 0; k < 64; k++) acc = fmaf(h[k], W2[k * 64 + d], acc);
    teo[bp * 64 + d] = acc;
}

// ---- fused main: FC_in + STE add + DCGRU L1 + DCGRU L2 (interleaved) + head
__global__ __launch_bounds__(256, 1) void gman_main(
    const float* __restrict__ X, const float* __restrict__ seT, const float* __restrict__ te,
    const float* __restrict__ Win1, const float* __restrict__ bin1, const float* __restrict__ Win2,
    const float* __restrict__ L1w, const float* __restrict__ L2w,
    const float* __restrict__ bg1, const float* __restrict__ bc1,
    const float* __restrict__ bg2, const float* __restrict__ bc2,
    const float* __restrict__ Wo1, const float* __restrict__ bo1,
    const float* __restrict__ Wo2, const float* __restrict__ bo2,
    float* __restrict__ out) {
    // 128 KB: s1 = [64][256] at float offset 0, s2 at 16384. Lane tid owns column tid:
    // addr k*256+tid -> lanes consecutive (2 lanes/bank = free), column-private -> no barriers.
    __shared__ float S[32768];

    const int tid = threadIdx.x;
    const int b = blockIdx.x >> 2;                          // uniform per block
    const int n = ((blockIdx.x & 3) << 8) | tid;            // coalesced lanes
    float* s1p = S + tid;                                   // s1[k] == s1p[k*256]
    float* s2p = S + 16384 + tid;

    const float* Wgx1 = L1w;          const float* Wgs1 = L1w + 8192;
    const float* Wcx1 = L1w + 16384;  const float* Wcs1 = L1w + 20480;
    const float* Wgx2 = L2w;          const float* Wgs2 = L2w + 8192;
    const float* Wcx2 = L2w + 16384;  const float* Wcs2 = L2w + 20480;

    #pragma unroll
    for (int d = 0; d < 64; d++) { s1p[d * 256] = 0.0f; s2p[d * 256] = 0.0f; }

    #pragma unroll 1
    for (int p = 0; p < 12; p++) {
        // ---------- xe = relu(x*Win1+bin1)@Win2 + bin2 + se[n] + te[b,p] ----------
        const float x = X[(b * 12 + p) * NB + n];
        const float* tep = te + (b * 12 + p) * 64;          // uniform -> s_load
        float xe[64];
        #pragma unroll
        for (int d = 0; d < 64; d++) xe[d] = seT[d * NB + n] + tep[d];
        #pragma unroll
        for (int j = 0; j < 64; j++) {
            float h = fmaxf(fmaf(x, Win1[j], bin1[j]), 0.0f);
            #pragma unroll
            for (int d = 0; d < 64; d++) xe[d] = fmaf(h, Win2[j * 64 + d], xe[d]);
        }
        // ---------- layer 1 (x-input = xe regs, state = s1 in LDS) ----------
        {
            float ga[64], c[64];
            // pass r: gate columns 0..63
            #pragma unroll
            for (int j = 0; j < 64; j++) ga[j] = bg1[j];
            #pragma unroll
            for (int k = 0; k < 64; k++) {
                const float sk = s1p[k * 256];
                const float xk = xe[k];
                #pragma unroll
                for (int j = 0; j < 64; j++)
                    ga[j] = fmaf(xk, Wgx1[k * 128 + j], fmaf(sk, Wgs1[k * 128 + j], ga[j]));
            }
            // candidate: consumes r = sigmoid(ga[k]) on the fly, uses OLD s1
            #pragma unroll
            for (int j = 0; j < 64; j++) c[j] = bc1[j];
            #pragma unroll
            for (int k = 0; k < 64; k++) {
                const float rk = fsigmoid(ga[k]) * s1p[k * 256];
                const float xk = xe[k];
                #pragma unroll
                for (int j = 0; j < 64; j++)
                    c[j] = fmaf(xk, Wcx1[k * 64 + j], fmaf(rk, Wcs1[k * 64 + j], c[j]));
            }
            // pass u: gate columns 64..127 (reuse ga)
            #pragma unroll
            for (int j = 0; j < 64; j++) ga[j] = bg1[64 + j];
            #pragma unroll
            for (int k = 0; k < 64; k++) {
                const float sk = s1p[k * 256];
                const float xk = xe[k];
                #pragma unroll
                for (int j = 0; j < 64; j++)
                    ga[j] = fmaf(xk, Wgx1[k * 128 + 64 + j], fmaf(sk, Wgs1[k * 128 + 64 + j], ga[j]));
            }
            // update s1 (in LDS)
            #pragma unroll
            for (int j = 0; j < 64; j++) {
                const float u = fsigmoid(ga[j]);
                const float sold = s1p[j * 256];
                s1p[j * 256] = u * sold + (1.0f - u) * ftanh(c[j]);
            }
        }
        // ---------- layer 2 (x-input = NEW s1 in LDS, state = s2 in LDS) ----------
        {
            float ga[64], c[64];
            #pragma unroll
            for (int j = 0; j < 64; j++) ga[j] = bg2[j];
            #pragma unroll
            for (int k = 0; k < 64; k++) {
                const float xk = s1p[k * 256];
                const float sk = s2p[k * 256];
                #pragma unroll
                for (int j = 0; j < 64; j++)
                    ga[j] = fmaf(xk, Wgx2[k * 128 + j], fmaf(sk, Wgs2[k * 128 + j], ga[j]));
            }
            #pragma unroll
            for (int j = 0; j < 64; j++) c[j] = bc2[j];
            #pragma unroll
            for (int k = 0; k < 64; k++) {
                const float rk = fsigmoid(ga[k]) * s2p[k * 256];
                const float xk = s1p[k * 256];
                #pragma unroll
                for (int j = 0; j < 64; j++)
                    c[j] = fmaf(xk, Wcx2[k * 64 + j], fmaf(rk, Wcs2[k * 64 + j], c[j]));
            }
            #pragma unroll
            for (int j = 0; j < 64; j++) ga[j] = bg2[64 + j];
            #pragma unroll
            for (int k = 0; k < 64; k++) {
                const float xk = s1p[k * 256];
                const float sk = s2p[k * 256];
                #pragma unroll
                for (int j = 0; j < 64; j++)
                    ga[j] = fmaf(xk, Wgx2[k * 128 + 64 + j], fmaf(sk, Wgs2[k * 128 + 64 + j], ga[j]));
            }
            #pragma unroll
            for (int j = 0; j < 64; j++) {
                const float u = fsigmoid(ga[j]);
                const float sold = s2p[j * 256];
                s2p[j * 256] = u * sold + (1.0f - u) * ftanh(c[j]);
            }
        }
    }
    // ---------- head: Y = relu(s2@Wo1+bo1)@Wo2+bo2, write transposed [B,Q,N] ----------
    {
        float h[64];
        #pragma unroll
        for (int j = 0; j < 64; j++) h[j] = bo1[j];
        #pragma unroll
        for (int k = 0; k < 64; k++) {
            const float s2k = s2p[k * 256];
            #pragma unroll
            for (int j = 0; j < 64; j++) h[j] = fmaf(s2k, Wo1[k * 64 + j], h[j]);
        }
        float y[12];
        #pragma unroll
        for (int q = 0; q < 12; q++) y[q] = bo2[q];
        #pragma unroll
        for (int j = 0; j < 64; j++) {
            const float hj = fmaxf(h[j], 0.0f);
            #pragma unroll
            for (int q = 0; q < 12; q++) y[q] = fmaf(hj, Wo2[j * 12 + q], y[q]);
        }
        #pragma unroll
        for (int q = 0; q < 12; q++) out[(b * 12 + q) * NB + n] = y[q];
    }
}

extern "C" void kernel_launch(void* const* d_in, const int* in_sizes, int n_in,
                              void* d_out, int out_size, void* d_ws, size_t ws_size,
                              hipStream_t stream) {
    const float* X    = (const float*)d_in[0];
    // d_in[1]=ZC, d_in[2]=ZF unused by the reference
    const float* SE   = (const float*)d_in[3];
    const float* Wse1 = (const float*)d_in[4];
    const float* bse1 = (const float*)d_in[5];
    const float* Wse2 = (const float*)d_in[6];
    const float* bse2 = (const float*)d_in[7];
    const float* Wte1 = (const float*)d_in[8];
    const float* bte1 = (const float*)d_in[9];
    const float* Wte2 = (const float*)d_in[10];
    const float* bte2 = (const float*)d_in[11];
    const float* Win1 = (const float*)d_in[12];
    const float* bin1 = (const float*)d_in[13];
    const float* Win2 = (const float*)d_in[14];
    const float* bin2 = (const float*)d_in[15];
    const float* Wg1  = (const float*)d_in[16];
    const float* bg1  = (const float*)d_in[17];
    const float* Wc1  = (const float*)d_in[18];
    const float* bc1  = (const float*)d_in[19];
    const float* Wg2  = (const float*)d_in[20];
    const float* bg2  = (const float*)d_in[21];
    const float* Wc2  = (const float*)d_in[22];
    const float* bc2  = (const float*)d_in[23];
    const float* Wo1  = (const float*)d_in[24];
    const float* bo1  = (const float*)d_in[25];
    const float* Wo2  = (const float*)d_in[26];
    const float* bo2  = (const float*)d_in[27];
    const int*   TE   = (const int*)d_in[28];

    float* ws  = (float*)d_ws;
    float* L1w = ws;                 //  24576 floats
    float* L2w = ws + 24576;         //  24576 floats
    float* seT = ws + 49152;         //  65536 floats (b_in2 folded in)
    float* teo = ws + 114688;        //  49152 floats  (total 640 KB)
    float* out = (float*)d_out;

    prep_weights<<<96, 256, 0, stream>>>(Wg1, Wc1, L1w);
    prep_weights<<<96, 256, 0, stream>>>(Wg2, Wc2, L2w);
    prep_se<<<1024, 64, 0, stream>>>(SE, Wse1, bse1, Wse2, bse2, bin2, seT);
    prep_te<<<768, 64, 0, stream>>>(TE, Wte1, bte1, Wte2, bte2, teo);
    gman_main<<<256, 256, 0, stream>>>(X, seT, teo, Win1, bin1, Win2, L1w, L2w,
                                       bg1, bc1, bg2, bc2, Wo1, bo1, Wo2, bo2, out);
}

// Round 3
// 5914.226 us; speedup vs baseline: 2.9462x; 2.9462x over previous
//
#include <hip/hip_runtime.h>

// GMAN-ish pipeline, fully fused. support = I so every (b,n) token is independent.
// B=64, P=Q=12, N=1024, D=64. Output [B,Q,N] fp32.
//
// R3: eliminate register spills for real (R2: 9 GB scratch traffic = 100% of runtime).
// Design rule: no phase may have >~160 live floats/lane; no register array may ever
// see a runtime index.
//  - s1/s2 states in LDS [64][256], lane-private columns (conflict-free, barrier-free).
//  - candidate x-part accumulated FIRST (xe64+c64=128 live),
//  - r-gates in k-chunks of 16, rs folded into c immediately (xe64+c64+gar16=144),
//  - u-gates in j-chunks of 16 (fully unrolled), c consumed as snew grows (~160 peak).
//  - layer 2 reads both inputs from LDS -> rolled k-loops, tiny register load.

#define NB 1024

__device__ __forceinline__ float fexp(float x) {
    return __builtin_amdgcn_exp2f(x * 1.44269504088896341f);
}
__device__ __forceinline__ float fsigmoid(float x) {
    return __builtin_amdgcn_rcpf(1.0f + fexp(-x));   // exp overflow -> inf -> rcp -> 0 : OK
}
__device__ __forceinline__ float ftanh(float x) {
    return 1.0f - 2.0f * __builtin_amdgcn_rcpf(1.0f + fexp(2.0f * x));  // saturates to +-1 : OK
}

// ---- collapse one DCGRU layer's weights: Wx = W[0:64]+W[128:192], Ws = W[64:128]+W[192:256]
// out layout (floats): Wgx [0,8192) Wgs [8192,16384) Wcx [16384,20480) Wcs [20480,24576)
__global__ void prep_weights(const float* __restrict__ Wg, const float* __restrict__ Wc,
                             float* __restrict__ o) {
    int i = blockIdx.x * 256 + threadIdx.x;
    if (i >= 24576) return;
    if (i < 8192) {
        int k = i >> 7, j = i & 127;
        o[i] = Wg[k * 128 + j] + Wg[(128 + k) * 128 + j];
    } else if (i < 16384) {
        int ii = i - 8192; int k = ii >> 7, j = ii & 127;
        o[i] = Wg[(64 + k) * 128 + j] + Wg[(192 + k) * 128 + j];
    } else if (i < 20480) {
        int ii = i - 16384; int k = ii >> 6, j = ii & 63;
        o[i] = Wc[k * 64 + j] + Wc[(128 + k) * 64 + j];
    } else {
        int ii = i - 20480; int k = ii >> 6, j = ii & 63;
        o[i] = Wc[(64 + k) * 64 + j] + Wc[(192 + k) * 64 + j];
    }
}

// ---- se = relu(SE@W1+b1)@W2+b2, stored TRANSPOSED [d][n] with b_in2 folded in.
__global__ void prep_se(const float* __restrict__ SE, const float* __restrict__ W1,
                        const float* __restrict__ b1, const float* __restrict__ W2,
                        const float* __restrict__ b2, const float* __restrict__ bin2,
                        float* __restrict__ seT) {
    __shared__ float h[64];
    int n = blockIdx.x, d = threadIdx.x;
    float acc = b1[d];
    for (int k = 0; k < 64; k++) acc = fmaf(SE[n * 64 + k], W1[k * 64 + d], acc);
    h[d] = fmaxf(acc, 0.0f);
    __syncthreads();
    float acc2 = b2[d];
    for (int k = 0; k < 64; k++) acc2 = fmaf(h[k], W2[k * 64 + d], acc2);
    seT[d * NB + n] = acc2 + bin2[d];
}

// ---- te[b,p,:] = relu(Wte1[dow]+Wte1[7+tod]+b1)@W2+b2   (one-hot matmul == row gather)
__global__ void prep_te(const int* __restrict__ TE, const float* __restrict__ W1,
                        const float* __restrict__ b1, const float* __restrict__ W2,
                        const float* __restrict__ b2, float* __restrict__ teo) {
    __shared__ float h[64];
    int bp = blockIdx.x;            // b*12 + p
    int b = bp / 12, p = bp - b * 12;
    int d = threadIdx.x;
    int dow = TE[(b * 24 + p) * 2 + 0];
    int tod = TE[(b * 24 + p) * 2 + 1];
    float v = W1[dow * 64 + d] + W1[(7 + tod) * 64 + d] + b1[d];
    h[d] = fmaxf(v, 0.0f);
    __syncthreads();
    float acc = b2[d];
    for (int k = 0; k < 64; k++) acc = fmaf(h[k], W2[k * 64 + d], acc);
    teo[bp * 64 + d] = acc;
}

// ---- fused main: FC_in + STE add + DCGRU L1 + DCGRU L2 (interleaved) + head
__global__ __launch_bounds__(256, 1) void gman_main(
    const float* __restrict__ X, const float* __restrict__ seT, const float* __restrict__ te,
    const float* __restrict__ Win1, const float* __restrict__ bin1, const float* __restrict__ Win2,
    const float* __restrict__ L1w, const float* __restrict__ L2w,
    const float* __restrict__ bg1, const float* __restrict__ bc1,
    const float* __restrict__ bg2, const float* __restrict__ bc2,
    const float* __restrict__ Wo1, const float* __restrict__ bo1,
    const float* __restrict__ Wo2, const float* __restrict__ bo2,
    float* __restrict__ out) {
    // 128 KB: s1 = [64][256] at float offset 0, s2 at 16384. Lane tid owns column tid:
    // addr k*256+tid -> 2 lanes/bank (free), column-private -> no barriers anywhere.
    __shared__ float S[32768];

    const int tid = threadIdx.x;
    const int b = blockIdx.x >> 2;                          // uniform per block
    const int n = ((blockIdx.x & 3) << 8) | tid;            // coalesced lanes
    float* s1p = S + tid;                                   // s1[k] == s1p[k*256]
    float* s2p = S + 16384 + tid;

    const float* Wgx1 = L1w;          const float* Wgs1 = L1w + 8192;
    const float* Wcx1 = L1w + 16384;  const float* Wcs1 = L1w + 20480;
    const float* Wgx2 = L2w;          const float* Wgs2 = L2w + 8192;
    const float* Wcx2 = L2w + 16384;  const float* Wcs2 = L2w + 20480;

    #pragma unroll
    for (int d = 0; d < 64; d++) { s1p[d * 256] = 0.0f; s2p[d * 256] = 0.0f; }

    #pragma unroll 1
    for (int p = 0; p < 12; p++) {
        const float x = X[(b * 12 + p) * NB + n];
        const float* tep = te + (b * 12 + p) * 64;          // uniform -> s_load

        // ---------- A: xe (regs) = se[n] + te[b,p] + relu(x*Win1+bin1)@Win2 (+bin2 folded) ----
        float xe[64];
        #pragma unroll
        for (int d = 0; d < 64; d++) xe[d] = seT[d * NB + n] + tep[d];
        #pragma unroll 4
        for (int j = 0; j < 64; j++) {
            const float h = fmaxf(fmaf(x, Win1[j], bin1[j]), 0.0f);
            #pragma unroll
            for (int d = 0; d < 64; d++) xe[d] = fmaf(h, Win2[j * 64 + d], xe[d]);
        }

        // =============== layer 1: x-input = xe (regs), state = s1 (LDS) ===============
        float c[64];
        // B1: candidate x-part first (live: xe64 + c64)
        #pragma unroll
        for (int j = 0; j < 64; j++) c[j] = bc1[j];
        #pragma unroll
        for (int k = 0; k < 64; k++) {
            const float xk = xe[k];
            #pragma unroll
            for (int j = 0; j < 64; j++) c[j] = fmaf(xk, Wcx1[k * 64 + j], c[j]);
        }
        // B2: r-gates in k-chunks of 16, fold rs into c immediately (live: xe+c+gar16)
        #pragma unroll 1
        for (int kc = 0; kc < 4; kc++) {
            float gar[16];
            #pragma unroll
            for (int j = 0; j < 16; j++) gar[j] = bg1[kc * 16 + j];
            #pragma unroll
            for (int k = 0; k < 64; k++) {
                const float xk = xe[k];
                const float sk = s1p[k * 256];
                #pragma unroll
                for (int j = 0; j < 16; j++)
                    gar[j] = fmaf(xk, Wgx1[k * 128 + kc * 16 + j],
                                  fmaf(sk, Wgs1[k * 128 + kc * 16 + j], gar[j]));
            }
            #pragma unroll
            for (int j = 0; j < 16; j++) {
                const float rs = fsigmoid(gar[j]) * s1p[(kc * 16 + j) * 256];
                #pragma unroll
                for (int jj = 0; jj < 64; jj++)
                    c[jj] = fmaf(rs, Wcs1[(kc * 16 + j) * 64 + jj], c[jj]);
            }
        }
        // B3: u-gates in j-chunks of 16 (FULLY unrolled: snew must never see runtime idx);
        //     c[jc] consumed as snew grows (live: xe + c(shrink) + snew(grow) + gau16)
        float snew[64];
        #pragma unroll
        for (int jc = 0; jc < 4; jc++) {
            float gau[16];
            #pragma unroll
            for (int j = 0; j < 16; j++) gau[j] = bg1[64 + jc * 16 + j];
            #pragma unroll
            for (int k = 0; k < 64; k++) {
                const float xk = xe[k];
                const float sk = s1p[k * 256];
                #pragma unroll
                for (int j = 0; j < 16; j++)
                    gau[j] = fmaf(xk, Wgx1[k * 128 + 64 + jc * 16 + j],
                                  fmaf(sk, Wgs1[k * 128 + 64 + jc * 16 + j], gau[j]));
            }
            #pragma unroll
            for (int j = 0; j < 16; j++) {
                const float u = fsigmoid(gau[j]);
                snew[jc * 16 + j] = u * s1p[(jc * 16 + j) * 256]
                                  + (1.0f - u) * ftanh(c[jc * 16 + j]);
            }
        }
        #pragma unroll
        for (int j = 0; j < 64; j++) s1p[j * 256] = snew[j];

        // =============== layer 2: x-input = s1 (LDS), state = s2 (LDS) ===============
        // C1: candidate x-part (rolled k: both inputs are LDS, no reg-array indexing)
        #pragma unroll
        for (int j = 0; j < 64; j++) c[j] = bc2[j];
        #pragma unroll 2
        for (int k = 0; k < 64; k++) {
            const float xk = s1p[k * 256];
            #pragma unroll
            for (int j = 0; j < 64; j++) c[j] = fmaf(xk, Wcx2[k * 64 + j], c[j]);
        }
        // C2: r-gates k-chunks of 16 + fold
        #pragma unroll 1
        for (int kc = 0; kc < 4; kc++) {
            float gar[16];
            #pragma unroll
            for (int j = 0; j < 16; j++) gar[j] = bg2[kc * 16 + j];
            #pragma unroll 2
            for (int k = 0; k < 64; k++) {
                const float xk = s1p[k * 256];
                const float sk = s2p[k * 256];
                #pragma unroll
                for (int j = 0; j < 16; j++)
                    gar[j] = fmaf(xk, Wgx2[k * 128 + kc * 16 + j],
                                  fmaf(sk, Wgs2[k * 128 + kc * 16 + j], gar[j]));
            }
            #pragma unroll
            for (int j = 0; j < 16; j++) {
                const float rs = fsigmoid(gar[j]) * s2p[(kc * 16 + j) * 256];
                #pragma unroll
                for (int jj = 0; jj < 64; jj++)
                    c[jj] = fmaf(rs, Wcs2[(kc * 16 + j) * 64 + jj], c[jj]);
            }
        }
        // C3: u-gates j-chunks (unrolled) + buffered update
        float snew2[64];
        #pragma unroll
        for (int jc = 0; jc < 4; jc++) {
            float gau[16];
            #pragma unroll
            for (int j = 0; j < 16; j++) gau[j] = bg2[64 + jc * 16 + j];
            #pragma unroll 2
            for (int k = 0; k < 64; k++) {
                const float xk = s1p[k * 256];
                const float sk = s2p[k * 256];
                #pragma unroll
                for (int j = 0; j < 16; j++)
                    gau[j] = fmaf(xk, Wgx2[k * 128 + 64 + jc * 16 + j],
                                  fmaf(sk, Wgs2[k * 128 + 64 + jc * 16 + j], gau[j]));
            }
            #pragma unroll
            for (int j = 0; j < 16; j++) {
                const float u = fsigmoid(gau[j]);
                snew2[jc * 16 + j] = u * s2p[(jc * 16 + j) * 256]
                                   + (1.0f - u) * ftanh(c[jc * 16 + j]);
            }
        }
        #pragma unroll
        for (int j = 0; j < 64; j++) s2p[j * 256] = snew2[j];
    }

    // ---------- head: Y = relu(s2@Wo1+bo1)@Wo2+bo2, write transposed [B,Q,N] ----------
    {
        float h[64];
        #pragma unroll
        for (int j = 0; j < 64; j++) h[j] = bo1[j];
        #pragma unroll 2
        for (int k = 0; k < 64; k++) {
            const float s2k = s2p[k * 256];
            #pragma unroll
            for (int j = 0; j < 64; j++) h[j] = fmaf(s2k, Wo1[k * 64 + j], h[j]);
        }
        float y[12];
        #pragma unroll
        for (int q = 0; q < 12; q++) y[q] = bo2[q];
        #pragma unroll
        for (int j = 0; j < 64; j++) {
            const float hj = fmaxf(h[j], 0.0f);
            #pragma unroll
            for (int q = 0; q < 12; q++) y[q] = fmaf(hj, Wo2[j * 12 + q], y[q]);
        }
        #pragma unroll
        for (int q = 0; q < 12; q++) out[(b * 12 + q) * NB + n] = y[q];
    }
}

extern "C" void kernel_launch(void* const* d_in, const int* in_sizes, int n_in,
                              void* d_out, int out_size, void* d_ws, size_t ws_size,
                              hipStream_t stream) {
    const float* X    = (const float*)d_in[0];
    // d_in[1]=ZC, d_in[2]=ZF unused by the reference
    const float* SE   = (const float*)d_in[3];
    const float* Wse1 = (const float*)d_in[4];
    const float* bse1 = (const float*)d_in[5];
    const float* Wse2 = (const float*)d_in[6];
    const float* bse2 = (const float*)d_in[7];
    const float* Wte1 = (const float*)d_in[8];
    const float* bte1 = (const float*)d_in[9];
    const float* Wte2 = (const float*)d_in[10];
    const float* bte2 = (const float*)d_in[11];
    const float* Win1 = (const float*)d_in[12];
    const float* bin1 = (const float*)d_in[13];
    const float* Win2 = (const float*)d_in[14];
    const float* bin2 = (const float*)d_in[15];
    const float* Wg1  = (const float*)d_in[16];
    const float* bg1  = (const float*)d_in[17];
    const float* Wc1  = (const float*)d_in[18];
    const float* bc1  = (const float*)d_in[19];
    const float* Wg2  = (const float*)d_in[20];
    const float* bg2  = (const float*)d_in[21];
    const float* Wc2  = (const float*)d_in[22];
    const float* bc2  = (const float*)d_in[23];
    const float* Wo1  = (const float*)d_in[24];
    const float* bo1  = (const float*)d_in[25];
    const float* Wo2  = (const float*)d_in[26];
    const float* bo2  = (const float*)d_in[27];
    const int*   TE   = (const int*)d_in[28];

    float* ws  = (float*)d_ws;
    float* L1w = ws;                 //  24576 floats
    float* L2w = ws + 24576;         //  24576 floats
    float* seT = ws + 49152;         //  65536 floats (b_in2 folded in)
    float* teo = ws + 114688;        //  49152 floats  (total 640 KB)
    float* out = (float*)d_out;

    prep_weights<<<96, 256, 0, stream>>>(Wg1, Wc1, L1w);
    prep_weights<<<96, 256, 0, stream>>>(Wg2, Wc2, L2w);
    prep_se<<<1024, 64, 0, stream>>>(SE, Wse1, bse1, Wse2, bse2, bin2, seT);
    prep_te<<<768, 64, 0, stream>>>(TE, Wte1, bte1, Wte2, bte2, teo);
    gman_main<<<256, 256, 0, stream>>>(X, seT, teo, Win1, bin1, Win2, L1w, L2w,
                                       bg1, bc1, bg2, bc2, Wo1, bo1, Wo2, bo2, out);
}